// Round 1
// baseline (4356.683 us; speedup 1.0000x reference)
//
#include <hip/hip_runtime.h>

constexpr int K = 128;

__global__ __launch_bounds__(256) void count_deg(const int* __restrict__ dst,
                                                 float* __restrict__ deg, int E) {
    int e = blockIdx.x * 256 + threadIdx.x;
    if (e < E) atomicAdd(&deg[dst[e]], 1.0f);
}

__global__ __launch_bounds__(256) void make_dinv(const float* __restrict__ deg,
                                                 float* __restrict__ dinv, int N) {
    int i = blockIdx.x * 256 + threadIdx.x;
    if (i < N) dinv[i] = rsqrtf(deg[i] + 1.0f);  // +1 = self-loop; always > 0
}

// H[M,N] = X[M,128] @ W[128,N]; optional ReLU applied to X on load.
template<int N, bool RELU>
__global__ __launch_bounds__(256) void gemm_xw(const float* __restrict__ X,
                                               const float* __restrict__ W,
                                               float* __restrict__ H, int M) {
    constexpr int TPR = N / 8;       // threads per row (each thread: 8 channels)
    constexpr int RPB = 256 / TPR;   // rows per block
    __shared__ float sW[K * N];
    __shared__ float sX[RPB][K + 1]; // +1 pad: r-groups land in distinct banks

    for (int i = threadIdx.x; i < K * N; i += 256) sW[i] = W[i];
    int row0 = blockIdx.x * RPB;
    for (int i = threadIdx.x; i < RPB * K; i += 256) {
        int r = i >> 7, k = i & 127;
        int gr = row0 + r;
        float v = (gr < M) ? X[(size_t)gr * K + k] : 0.0f;
        if (RELU) v = fmaxf(v, 0.0f);
        sX[r][k] = v;
    }
    __syncthreads();

    int tr = threadIdx.x % TPR;
    int r  = threadIdx.x / TPR;
    int c0 = tr * 8;
    float acc[8] = {0.f,0.f,0.f,0.f,0.f,0.f,0.f,0.f};
    #pragma unroll 4
    for (int k = 0; k < K; ++k) {
        float xv = sX[r][k];
        const float4 w0 = *reinterpret_cast<const float4*>(&sW[k * N + c0]);
        const float4 w1 = *reinterpret_cast<const float4*>(&sW[k * N + c0 + 4]);
        acc[0] = fmaf(xv, w0.x, acc[0]);
        acc[1] = fmaf(xv, w0.y, acc[1]);
        acc[2] = fmaf(xv, w0.z, acc[2]);
        acc[3] = fmaf(xv, w0.w, acc[3]);
        acc[4] = fmaf(xv, w1.x, acc[4]);
        acc[5] = fmaf(xv, w1.y, acc[5]);
        acc[6] = fmaf(xv, w1.z, acc[6]);
        acc[7] = fmaf(xv, w1.w, acc[7]);
    }
    int gr = row0 + r;
    if (gr < M) {
        float4* o = reinterpret_cast<float4*>(&H[(size_t)gr * N + c0]);
        o[0] = make_float4(acc[0], acc[1], acc[2], acc[3]);
        o[1] = make_float4(acc[4], acc[5], acc[6], acc[7]);
    }
}

// AGG[i,c] = T[i,c]*dinv[i]^2 + bias[c]   (self-loop message + bias, full init)
template<int C>
__global__ __launch_bounds__(256) void init_agg(const float* __restrict__ T,
                                                const float* __restrict__ dinv,
                                                const float* __restrict__ bias,
                                                float* __restrict__ AGG, int N) {
    constexpr int C4 = C / 4;
    int idx = blockIdx.x * 256 + threadIdx.x;   // over N*C4 float4's
    if (idx >= N * C4) return;
    int node = idx / C4;
    int c4   = idx % C4;
    float di = dinv[node];
    float s  = di * di;
    float4 t = reinterpret_cast<const float4*>(T)[idx];
    float4 b = reinterpret_cast<const float4*>(bias)[c4];
    float4 o;
    o.x = fmaf(t.x, s, b.x);
    o.y = fmaf(t.y, s, b.y);
    o.z = fmaf(t.z, s, b.z);
    o.w = fmaf(t.w, s, b.w);
    reinterpret_cast<float4*>(AGG)[idx] = o;
}

// For each edge e: AGG[dst[e]] += H[src[e]] * dinv[src]*dinv[dst]
template<int C>
__global__ __launch_bounds__(256) void scatter_edges(const float* __restrict__ H,
                                                     const int* __restrict__ src,
                                                     const int* __restrict__ dst,
                                                     const float* __restrict__ dinv,
                                                     float* __restrict__ AGG, int E) {
    constexpr int TPE = C / 4;                  // threads per edge (float4 each)
    long long t = (long long)blockIdx.x * 256 + threadIdx.x;
    int e = (int)(t / TPE);
    if (e >= E) return;
    int lane = (int)(t % TPE);
    int s = src[e], d = dst[e];
    float norm = dinv[s] * dinv[d];
    const float4 v = *reinterpret_cast<const float4*>(&H[(size_t)s * C + lane * 4]);
    float* o = &AGG[(size_t)d * C + lane * 4];
    atomicAdd(o + 0, v.x * norm);
    atomicAdd(o + 1, v.y * norm);
    atomicAdd(o + 2, v.z * norm);
    atomicAdd(o + 3, v.w * norm);
}

extern "C" void kernel_launch(void* const* d_in, const int* in_sizes, int n_in,
                              void* d_out, int out_size, void* d_ws, size_t ws_size,
                              hipStream_t stream) {
    const float* x  = (const float*)d_in[0];
    const int*   ei = (const int*)d_in[1];   // int32 (JAX canonicalizes int64)
    const float* W1 = (const float*)d_in[2];
    const float* b1 = (const float*)d_in[3];
    const float* W2 = (const float*)d_in[4];
    const float* b2 = (const float*)d_in[5];
    float* out = (float*)d_out;

    const int N = in_sizes[0] / 128;
    const int E = in_sizes[1] / 2;
    const int* src = ei;
    const int* dst = ei + E;

    float* ws   = (float*)d_ws;
    float* deg  = ws;                         // N
    float* dinv = ws + N;                     // N
    float* h1   = ws + 2 * (size_t)N;         // N*128
    float* agg1 = h1 + (size_t)N * 128;       // N*128
    float* t2   = agg1 + (size_t)N * 128;     // N*64

    // --- degrees (target-side, incl. self-loop) ---
    hipMemsetAsync(deg, 0, (size_t)N * sizeof(float), stream);
    count_deg<<<(E + 255) / 256, 256, 0, stream>>>(dst, deg, E);
    make_dinv<<<(N + 255) / 256, 256, 0, stream>>>(deg, dinv, N);

    // --- layer 1: h1 = x@W1; agg1 = self-loop + b1; scatter edges ---
    gemm_xw<128, false><<<(N + 15) / 16, 256, 0, stream>>>(x, W1, h1, N);
    init_agg<128><<<(int)(((size_t)N * 32 + 255) / 256), 256, 0, stream>>>(h1, dinv, b1, agg1, N);
    scatter_edges<128><<<(int)(((size_t)E * 32 + 255) / 256), 256, 0, stream>>>(h1, src, dst, dinv, agg1, E);

    // --- layer 2: t2 = relu(agg1)@W2; out = self-loop + b2; scatter edges ---
    gemm_xw<64, true><<<(N + 31) / 32, 256, 0, stream>>>(agg1, W2, t2, N);
    init_agg<64><<<(int)(((size_t)N * 16 + 255) / 256), 256, 0, stream>>>(t2, dinv, b2, out, N);
    scatter_edges<64><<<(int)(((size_t)E * 16 + 255) / 256), 256, 0, stream>>>(t2, src, dst, dinv, out, E);
}

// Round 2
// 630.039 us; speedup vs baseline: 6.9149x; 6.9149x over previous
//
#include <hip/hip_runtime.h>

constexpr int K = 128;

// ---------------- degree / binning ----------------

__global__ __launch_bounds__(256) void count_deg(const int* __restrict__ dst,
                                                 int* __restrict__ deg, int E) {
    int e = blockIdx.x * 256 + threadIdx.x;
    if (e < E) atomicAdd(&deg[dst[e]], 1);
}

__global__ __launch_bounds__(256) void make_dinv(const int* __restrict__ deg,
                                                 float* __restrict__ dinv, int N) {
    int i = blockIdx.x * 256 + threadIdx.x;
    if (i < N) dinv[i] = rsqrtf((float)deg[i] + 1.0f);  // +1 = self-loop
}

// scan level 1: per-block exclusive scan over 1024 ints; block total -> bsums
__global__ __launch_bounds__(256) void scan_block(const int* __restrict__ deg,
                                                  int* __restrict__ exc,
                                                  int* __restrict__ bsums, int N) {
    __shared__ int s[256];
    int base = blockIdx.x * 1024;
    int t = threadIdx.x;
    int v[4]; int sum = 0;
    #pragma unroll
    for (int k = 0; k < 4; ++k) {
        int idx = base + t * 4 + k;
        v[k] = (idx < N) ? deg[idx] : 0;
        sum += v[k];
    }
    s[t] = sum; __syncthreads();
    for (int off = 1; off < 256; off <<= 1) {
        int x = (t >= off) ? s[t - off] : 0;
        __syncthreads();
        s[t] += x;
        __syncthreads();
    }
    int run = s[t] - sum;  // exclusive prefix of this thread's chunk
    #pragma unroll
    for (int k = 0; k < 4; ++k) {
        int idx = base + t * 4 + k;
        if (idx < N) exc[idx] = run;
        run += v[k];
    }
    if (t == 255) bsums[blockIdx.x] = s[255];
}

// scan level 2: single block, exclusive scan of block sums (nb <= 256)
__global__ __launch_bounds__(256) void scan_sums(int* __restrict__ bsums, int nb) {
    __shared__ int s[256];
    int t = threadIdx.x;
    int v = (t < nb) ? bsums[t] : 0;
    s[t] = v; __syncthreads();
    for (int off = 1; off < 256; off <<= 1) {
        int x = (t >= off) ? s[t - off] : 0;
        __syncthreads();
        s[t] += x;
        __syncthreads();
    }
    if (t < nb) bsums[t] = s[t] - v;  // exclusive
}

// scan level 3: final offsets; also seed the fill cursor (aliases exc buffer)
__global__ __launch_bounds__(256) void scan_add(const int* __restrict__ bsums,
                                                int* __restrict__ exc_cursor,
                                                int* __restrict__ offs, int N, int E) {
    int i = blockIdx.x * 256 + threadIdx.x;
    if (i < N) {
        int o = exc_cursor[i] + bsums[i >> 10];
        offs[i] = o;
        exc_cursor[i] = o;  // becomes the cursor
    }
    if (i == 0) offs[N] = E;
}

__global__ __launch_bounds__(256) void fill_bins(const int* __restrict__ src,
                                                 const int* __restrict__ dst,
                                                 int* __restrict__ cursor,
                                                 int* __restrict__ esrc, int E) {
    int e = blockIdx.x * 256 + threadIdx.x;
    if (e < E) {
        int pos = atomicAdd(&cursor[dst[e]], 1);
        esrc[pos] = src[e];
    }
}

// ---------------- GEMM: H[M,N] = X[M,128] @ W[128,N], optional ReLU on X ----

template<int N, bool RELU>
__global__ __launch_bounds__(256) void gemm_xw(const float* __restrict__ X,
                                               const float* __restrict__ W,
                                               float* __restrict__ H, int M) {
    constexpr int TPR = N / 8;       // threads per row (each thread: 8 channels)
    constexpr int RPB = 256 / TPR;   // rows per block
    __shared__ float sW[K * N];
    __shared__ float sX[RPB][K + 1];

    for (int i = threadIdx.x; i < K * N; i += 256) sW[i] = W[i];
    int row0 = blockIdx.x * RPB;
    for (int i = threadIdx.x; i < RPB * K; i += 256) {
        int r = i >> 7, k = i & 127;
        int gr = row0 + r;
        float v = (gr < M) ? X[(size_t)gr * K + k] : 0.0f;
        if (RELU) v = fmaxf(v, 0.0f);
        sX[r][k] = v;
    }
    __syncthreads();

    int tr = threadIdx.x % TPR;
    int r  = threadIdx.x / TPR;
    int c0 = tr * 8;
    float acc[8] = {0.f,0.f,0.f,0.f,0.f,0.f,0.f,0.f};
    #pragma unroll 4
    for (int k = 0; k < K; ++k) {
        float xv = sX[r][k];
        const float4 w0 = *reinterpret_cast<const float4*>(&sW[k * N + c0]);
        const float4 w1 = *reinterpret_cast<const float4*>(&sW[k * N + c0 + 4]);
        acc[0] = fmaf(xv, w0.x, acc[0]);
        acc[1] = fmaf(xv, w0.y, acc[1]);
        acc[2] = fmaf(xv, w0.z, acc[2]);
        acc[3] = fmaf(xv, w0.w, acc[3]);
        acc[4] = fmaf(xv, w1.x, acc[4]);
        acc[5] = fmaf(xv, w1.y, acc[5]);
        acc[6] = fmaf(xv, w1.z, acc[6]);
        acc[7] = fmaf(xv, w1.w, acc[7]);
    }
    int gr = row0 + r;
    if (gr < M) {
        float4* o = reinterpret_cast<float4*>(&H[(size_t)gr * N + c0]);
        o[0] = make_float4(acc[0], acc[1], acc[2], acc[3]);
        o[1] = make_float4(acc[4], acc[5], acc[6], acc[7]);
    }
}

// ---------------- gather: AGG[i] = b + H[i]*dinv[i]^2 + sum_j H[src_j]*dinv[src_j]*dinv[i]

template<int C>
__global__ __launch_bounds__(256) void gather_nodes(const float* __restrict__ H,
                                                    const int* __restrict__ esrc,
                                                    const int* __restrict__ offs,
                                                    const float* __restrict__ dinv,
                                                    const float* __restrict__ bias,
                                                    float* __restrict__ AGG, int N) {
    constexpr int TPN = C / 4;  // threads per node, one float4 each
    int gid = blockIdx.x * 256 + threadIdx.x;
    int node = gid / TPN;
    if (node >= N) return;
    int lane = gid % TPN;

    float di = dinv[node];
    float s2 = di * di;
    float4 b = reinterpret_cast<const float4*>(bias)[lane];
    float4 hs = reinterpret_cast<const float4*>(&H[(size_t)node * C])[lane];
    float4 acc;
    acc.x = fmaf(hs.x, s2, b.x);
    acc.y = fmaf(hs.y, s2, b.y);
    acc.z = fmaf(hs.z, s2, b.z);
    acc.w = fmaf(hs.w, s2, b.w);

    int j0 = offs[node], j1 = offs[node + 1];
    int j = j0;
    for (; j + 1 < j1; j += 2) {
        int s0 = esrc[j], s1 = esrc[j + 1];
        float n0 = dinv[s0] * di;
        float n1 = dinv[s1] * di;
        float4 v0 = reinterpret_cast<const float4*>(&H[(size_t)s0 * C])[lane];
        float4 v1 = reinterpret_cast<const float4*>(&H[(size_t)s1 * C])[lane];
        acc.x = fmaf(v0.x, n0, acc.x); acc.x = fmaf(v1.x, n1, acc.x);
        acc.y = fmaf(v0.y, n0, acc.y); acc.y = fmaf(v1.y, n1, acc.y);
        acc.z = fmaf(v0.z, n0, acc.z); acc.z = fmaf(v1.z, n1, acc.z);
        acc.w = fmaf(v0.w, n0, acc.w); acc.w = fmaf(v1.w, n1, acc.w);
    }
    if (j < j1) {
        int s0 = esrc[j];
        float n0 = dinv[s0] * di;
        float4 v0 = reinterpret_cast<const float4*>(&H[(size_t)s0 * C])[lane];
        acc.x = fmaf(v0.x, n0, acc.x);
        acc.y = fmaf(v0.y, n0, acc.y);
        acc.z = fmaf(v0.z, n0, acc.z);
        acc.w = fmaf(v0.w, n0, acc.w);
    }
    reinterpret_cast<float4*>(&AGG[(size_t)node * C])[lane] = acc;
}

// ---------------- launch ----------------

extern "C" void kernel_launch(void* const* d_in, const int* in_sizes, int n_in,
                              void* d_out, int out_size, void* d_ws, size_t ws_size,
                              hipStream_t stream) {
    const float* x  = (const float*)d_in[0];
    const int*   ei = (const int*)d_in[1];   // int32 (JAX canonicalizes int64)
    const float* W1 = (const float*)d_in[2];
    const float* b1 = (const float*)d_in[3];
    const float* W2 = (const float*)d_in[4];
    const float* b2 = (const float*)d_in[5];
    float* out = (float*)d_out;

    const int N = in_sizes[0] / 128;
    const int E = in_sizes[1] / 2;
    const int* src = ei;
    const int* dst = ei + E;

    // workspace layout (all 4B elems; region starts multiple-of-4 elems for float4)
    int*   deg    = (int*)d_ws;                     // N
    int*   excur  = deg + N;                        // N  (exclusive scan, then cursor)
    int*   bsums  = excur + N;                      // 1024
    int*   offs   = bsums + 1024;                   // N+8 (padded)
    float* dinv   = (float*)(offs + N + 8);         // N
    int*   esrc   = (int*)(dinv + N);               // E
    float* h1     = (float*)(esrc + E);             // N*128
    float* agg1   = h1 + (size_t)N * 128;           // N*128
    float* t2     = h1;                             // alias: h1 dead before t2 written

    const int nb = (N + 1023) / 1024;               // 98 for N=100000 (<=256)

    // --- binning (shared by both layers) ---
    hipMemsetAsync(deg, 0, (size_t)N * sizeof(int), stream);
    count_deg<<<(E + 255) / 256, 256, 0, stream>>>(dst, deg, E);
    make_dinv<<<(N + 255) / 256, 256, 0, stream>>>(deg, dinv, N);
    scan_block<<<nb, 256, 0, stream>>>(deg, excur, bsums, N);
    scan_sums<<<1, 256, 0, stream>>>(bsums, nb);
    scan_add<<<(N + 255) / 256, 256, 0, stream>>>(bsums, excur, offs, N, E);
    fill_bins<<<(E + 255) / 256, 256, 0, stream>>>(src, dst, excur, esrc, E);

    // --- layer 1: h1 = x@W1; agg1 = gather(h1) + selfloop + b1 ---
    gemm_xw<128, false><<<(N + 15) / 16, 256, 0, stream>>>(x, W1, h1, N);
    gather_nodes<128><<<(int)(((size_t)N * 32 + 255) / 256), 256, 0, stream>>>(
        h1, esrc, offs, dinv, b1, agg1, N);

    // --- layer 2: t2 = relu(agg1)@W2; out = gather(t2) + selfloop + b2 ---
    gemm_xw<64, true><<<(N + 31) / 32, 256, 0, stream>>>(agg1, W2, t2, N);
    gather_nodes<64><<<(int)(((size_t)N * 16 + 255) / 256), 256, 0, stream>>>(
        t2, esrc, offs, dinv, b2, out, N);
}

// Round 3
// 442.058 us; speedup vs baseline: 9.8555x; 1.4252x over previous
//
#include <hip/hip_runtime.h>
#include <hip/hip_fp16.h>

// ---------------- degree / binning ----------------

__global__ __launch_bounds__(256) void count_deg(const int* __restrict__ dst,
                                                 int* __restrict__ deg, int E) {
    int e = blockIdx.x * 256 + threadIdx.x;
    if (e < E) atomicAdd(&deg[dst[e]], 1);
}

__global__ __launch_bounds__(256) void make_dinv(const int* __restrict__ deg,
                                                 float* __restrict__ dinv, int N) {
    int i = blockIdx.x * 256 + threadIdx.x;
    if (i < N) dinv[i] = rsqrtf((float)deg[i] + 1.0f);  // +1 = self-loop
}

__global__ __launch_bounds__(256) void scan_block(const int* __restrict__ deg,
                                                  int* __restrict__ exc,
                                                  int* __restrict__ bsums, int N) {
    __shared__ int s[256];
    int base = blockIdx.x * 1024;
    int t = threadIdx.x;
    int v[4]; int sum = 0;
    #pragma unroll
    for (int k = 0; k < 4; ++k) {
        int idx = base + t * 4 + k;
        v[k] = (idx < N) ? deg[idx] : 0;
        sum += v[k];
    }
    s[t] = sum; __syncthreads();
    for (int off = 1; off < 256; off <<= 1) {
        int x = (t >= off) ? s[t - off] : 0;
        __syncthreads();
        s[t] += x;
        __syncthreads();
    }
    int run = s[t] - sum;
    #pragma unroll
    for (int k = 0; k < 4; ++k) {
        int idx = base + t * 4 + k;
        if (idx < N) exc[idx] = run;
        run += v[k];
    }
    if (t == 255) bsums[blockIdx.x] = s[255];
}

__global__ __launch_bounds__(256) void scan_sums(int* __restrict__ bsums, int nb) {
    __shared__ int s[256];
    int t = threadIdx.x;
    int v = (t < nb) ? bsums[t] : 0;
    s[t] = v; __syncthreads();
    for (int off = 1; off < 256; off <<= 1) {
        int x = (t >= off) ? s[t - off] : 0;
        __syncthreads();
        s[t] += x;
        __syncthreads();
    }
    if (t < nb) bsums[t] = s[t] - v;
}

__global__ __launch_bounds__(256) void scan_add(const int* __restrict__ bsums,
                                                int* __restrict__ exc_cursor,
                                                int* __restrict__ offs, int N, int E) {
    int i = blockIdx.x * 256 + threadIdx.x;
    if (i < N) {
        int o = exc_cursor[i] + bsums[i >> 10];
        offs[i] = o;
        exc_cursor[i] = o;
    }
    if (i == 0) offs[N] = E;
}

__global__ __launch_bounds__(256) void fill_bins(const int* __restrict__ src,
                                                 const int* __restrict__ dst,
                                                 int* __restrict__ cursor,
                                                 int* __restrict__ esrc, int E) {
    int e = blockIdx.x * 256 + threadIdx.x;
    if (e < E) {
        int pos = atomicAdd(&cursor[dst[e]], 1);
        esrc[pos] = src[e];
    }
}

// ---------------- GEMM: H[M,NC](fp16) = X[M,128](fp32) @ W[128,NC], opt ReLU on X

template<int NC, bool RELU>
__global__ __launch_bounds__(256) void gemm_xw(const float* __restrict__ X,
                                               const float* __restrict__ W,
                                               __half* __restrict__ H, int M) {
    constexpr int BM = 128, BK = 32;
    constexpr int CPT = NC / 16;              // cols per thread: 8 (NC=128) / 4 (NC=64)
    __shared__ float sX[BK][BM + 4];          // transposed X tile; +4 keeps b128 align
    __shared__ float sW[BK][NC];

    const int tid = threadIdx.x;
    const int tc = tid & 15, tr = tid >> 4;
    const int c0 = tc * CPT, r0 = tr * 8;
    const int row0 = blockIdx.x * BM;

    float acc[8][CPT];
    #pragma unroll
    for (int i = 0; i < 8; ++i)
        #pragma unroll
        for (int j = 0; j < CPT; ++j) acc[i][j] = 0.f;

    const int lfi = tid & 7;     // which float4 of the 32-k slice
    const int llr = tid >> 3;    // row 0..31 (stride 32)

    for (int kt = 0; kt < 128; kt += BK) {
        // stage X transposed: sX[k][row]
        #pragma unroll
        for (int rr = 0; rr < 4; ++rr) {
            int lr = llr + rr * 32;
            int gr = row0 + lr;
            float4 v = make_float4(0.f, 0.f, 0.f, 0.f);
            if (gr < M) v = *reinterpret_cast<const float4*>(&X[(size_t)gr * 128 + kt + lfi * 4]);
            if (RELU) {
                v.x = fmaxf(v.x, 0.f); v.y = fmaxf(v.y, 0.f);
                v.z = fmaxf(v.z, 0.f); v.w = fmaxf(v.w, 0.f);
            }
            sX[lfi * 4 + 0][lr] = v.x;
            sX[lfi * 4 + 1][lr] = v.y;
            sX[lfi * 4 + 2][lr] = v.z;
            sX[lfi * 4 + 3][lr] = v.w;
        }
        // stage W: direct copy (rows kt..kt+31, all NC cols)
        {
            constexpr int F4 = (BK * NC / 4) / 256;   // 4 (NC=128) / 2 (NC=64)
            #pragma unroll
            for (int q = 0; q < F4; ++q) {
                int idx = q * 256 + tid;
                int kr = idx / (NC / 4);
                int cc = (idx % (NC / 4)) * 4;
                *reinterpret_cast<float4*>(&sW[kr][cc]) =
                    *reinterpret_cast<const float4*>(&W[(size_t)(kt + kr) * NC + cc]);
            }
        }
        __syncthreads();

        #pragma unroll 8
        for (int k = 0; k < BK; ++k) {
            float a[8];
            *reinterpret_cast<float4*>(&a[0]) = *reinterpret_cast<const float4*>(&sX[k][r0]);
            *reinterpret_cast<float4*>(&a[4]) = *reinterpret_cast<const float4*>(&sX[k][r0 + 4]);
            float b[CPT];
            #pragma unroll
            for (int j = 0; j < CPT; j += 4)
                *reinterpret_cast<float4*>(&b[j]) = *reinterpret_cast<const float4*>(&sW[k][c0 + j]);
            #pragma unroll
            for (int i = 0; i < 8; ++i)
                #pragma unroll
                for (int j = 0; j < CPT; ++j)
                    acc[i][j] = fmaf(a[i], b[j], acc[i][j]);
        }
        __syncthreads();
    }

    #pragma unroll
    for (int i = 0; i < 8; ++i) {
        int gr = row0 + r0 + i;
        if (gr < M) {
            union { __half h[8]; uint4 u4; uint2 u2; } o;
            #pragma unroll
            for (int j = 0; j < CPT; ++j) o.h[j] = __float2half(acc[i][j]);
            if constexpr (CPT == 8)
                *reinterpret_cast<uint4*>(&H[(size_t)gr * NC + c0]) = o.u4;
            else
                *reinterpret_cast<uint2*>(&H[(size_t)gr * NC + c0]) = o.u2;
        }
    }
}

// ---------------- gather: AGG[i](fp32) = b + H[i]*dinv[i]^2 + sum_j H[s_j]*dinv[s_j]*dinv[i]
// H is fp16, C channels; C/8 threads per node, 8 channels (16B) each.

template<int C>
__global__ __launch_bounds__(256) void gather_nodes(const __half* __restrict__ H,
                                                    const int* __restrict__ esrc,
                                                    const int* __restrict__ offs,
                                                    const float* __restrict__ dinv,
                                                    const float* __restrict__ bias,
                                                    float* __restrict__ AGG, int N) {
    constexpr int TPN = C / 8;
    int gid = blockIdx.x * 256 + threadIdx.x;
    int node = gid / TPN;
    if (node >= N) return;
    int lane = gid % TPN;

    float di = dinv[node];
    float s2 = di * di;
    float acc[8];
    {
        uint4 raw = *reinterpret_cast<const uint4*>(H + (size_t)node * C + lane * 8);
        const __half2* h2 = reinterpret_cast<const __half2*>(&raw);
        #pragma unroll
        for (int q = 0; q < 4; ++q) {
            float2 f = __half22float2(h2[q]);
            acc[2*q]   = fmaf(f.x, s2, bias[lane * 8 + 2*q]);
            acc[2*q+1] = fmaf(f.y, s2, bias[lane * 8 + 2*q+1]);
        }
    }

    int j0 = offs[node], j1 = offs[node + 1];
    int j = j0;
    for (; j + 1 < j1; j += 2) {
        int s0 = esrc[j], s1 = esrc[j + 1];
        float n0 = dinv[s0] * di;
        float n1 = dinv[s1] * di;
        uint4 r0 = *reinterpret_cast<const uint4*>(H + (size_t)s0 * C + lane * 8);
        uint4 r1 = *reinterpret_cast<const uint4*>(H + (size_t)s1 * C + lane * 8);
        const __half2* a0 = reinterpret_cast<const __half2*>(&r0);
        const __half2* a1 = reinterpret_cast<const __half2*>(&r1);
        #pragma unroll
        for (int q = 0; q < 4; ++q) {
            float2 f0 = __half22float2(a0[q]);
            float2 f1 = __half22float2(a1[q]);
            acc[2*q]   = fmaf(f0.x, n0, acc[2*q]);
            acc[2*q+1] = fmaf(f0.y, n0, acc[2*q+1]);
            acc[2*q]   = fmaf(f1.x, n1, acc[2*q]);
            acc[2*q+1] = fmaf(f1.y, n1, acc[2*q+1]);
        }
    }
    if (j < j1) {
        int s0 = esrc[j];
        float n0 = dinv[s0] * di;
        uint4 r0 = *reinterpret_cast<const uint4*>(H + (size_t)s0 * C + lane * 8);
        const __half2* a0 = reinterpret_cast<const __half2*>(&r0);
        #pragma unroll
        for (int q = 0; q < 4; ++q) {
            float2 f0 = __half22float2(a0[q]);
            acc[2*q]   = fmaf(f0.x, n0, acc[2*q]);
            acc[2*q+1] = fmaf(f0.y, n0, acc[2*q+1]);
        }
    }

    float4* o = reinterpret_cast<float4*>(AGG + (size_t)node * C + lane * 8);
    o[0] = make_float4(acc[0], acc[1], acc[2], acc[3]);
    o[1] = make_float4(acc[4], acc[5], acc[6], acc[7]);
}

// ---------------- launch ----------------

extern "C" void kernel_launch(void* const* d_in, const int* in_sizes, int n_in,
                              void* d_out, int out_size, void* d_ws, size_t ws_size,
                              hipStream_t stream) {
    const float* x  = (const float*)d_in[0];
    const int*   ei = (const int*)d_in[1];   // int32 (JAX canonicalizes int64)
    const float* W1 = (const float*)d_in[2];
    const float* b1 = (const float*)d_in[3];
    const float* W2 = (const float*)d_in[4];
    const float* b2 = (const float*)d_in[5];
    float* out = (float*)d_out;

    const int N = in_sizes[0] / 128;
    const int E = in_sizes[1] / 2;
    const int* src = ei;
    const int* dst = ei + E;

    // workspace layout (all 16B-aligned segments)
    int*    deg   = (int*)d_ws;                    // N
    int*    excur = deg + N;                       // N
    int*    bsums = excur + N;                     // 1024
    int*    offs  = bsums + 1024;                  // N+8
    float*  dinv  = (float*)(offs + N + 8);        // N
    int*    esrc  = (int*)(dinv + N);              // E
    __half* h1    = (__half*)(esrc + E);           // N*128 halves
    float*  agg1  = (float*)(h1 + (size_t)N * 128);// N*128 floats
    __half* t2    = h1;                            // alias: h1 dead before t2 written

    const int nb = (N + 1023) / 1024;

    // --- binning (shared by both layers) ---
    hipMemsetAsync(deg, 0, (size_t)N * sizeof(int), stream);
    count_deg<<<(E + 255) / 256, 256, 0, stream>>>(dst, deg, E);
    make_dinv<<<(N + 255) / 256, 256, 0, stream>>>(deg, dinv, N);
    scan_block<<<nb, 256, 0, stream>>>(deg, excur, bsums, N);
    scan_sums<<<1, 256, 0, stream>>>(bsums, nb);
    scan_add<<<(N + 255) / 256, 256, 0, stream>>>(bsums, excur, offs, N, E);
    fill_bins<<<(E + 255) / 256, 256, 0, stream>>>(src, dst, excur, esrc, E);

    // --- layer 1 ---
    gemm_xw<128, false><<<(N + 127) / 128, 256, 0, stream>>>(x, W1, h1, N);
    gather_nodes<128><<<(int)(((size_t)N * 16 + 255) / 256), 256, 0, stream>>>(
        h1, esrc, offs, dinv, b1, agg1, N);

    // --- layer 2 ---
    gemm_xw<64, true><<<(N + 127) / 128, 256, 0, stream>>>(agg1, W2, t2, N);
    gather_nodes<64><<<(int)(((size_t)N * 8 + 255) / 256), 256, 0, stream>>>(
        t2, esrc, offs, dinv, b2, out, N);
}

// Round 4
// 394.548 us; speedup vs baseline: 11.0422x; 1.1204x over previous
//
#include <hip/hip_runtime.h>
#include <hip/hip_fp16.h>

// ---------------- coarse bucketing (counting sort, pass 1) ----------------

constexpr int NBK = 128;   // bucket slots (actual buckets = ((N-1)>>shift)+1 <= 128)

__global__ __launch_bounds__(256) void bucket_hist(const int* __restrict__ dst, int E,
                                                   int shift, int* __restrict__ bcnt) {
    __shared__ int h[NBK];
    int t = threadIdx.x;
    if (t < NBK) h[t] = 0;
    __syncthreads();
    for (int e = blockIdx.x * 256 + t; e < E; e += gridDim.x * 256)
        atomicAdd(&h[dst[e] >> shift], 1);
    __syncthreads();
    if (t < NBK && h[t]) atomicAdd(&bcnt[t], h[t]);
}

// exclusive scan of bcnt -> bcursor (single block, NBK threads)
__global__ __launch_bounds__(NBK) void bucket_scan(const int* __restrict__ bcnt,
                                                   int* __restrict__ bcursor) {
    __shared__ int s[NBK];
    int t = threadIdx.x;
    int v = bcnt[t];
    s[t] = v; __syncthreads();
    for (int off = 1; off < NBK; off <<= 1) {
        int x = (t >= off) ? s[t - off] : 0;
        __syncthreads();
        s[t] += x;
        __syncthreads();
    }
    bcursor[t] = s[t] - v;  // exclusive
}

// scatter edges into bucket-ordered pair array
__global__ __launch_bounds__(256) void bucket_scatter(const int* __restrict__ src,
                                                      const int* __restrict__ dst, int E,
                                                      int shift, int* __restrict__ bcursor,
                                                      int2* __restrict__ epair) {
    constexpr int ITER = 16;                 // 4096 edges per block
    __shared__ int lcnt[NBK];
    __shared__ int lbase[NBK];
    int t = threadIdx.x;
    int base = blockIdx.x * 256 * ITER;
    int s[ITER], d[ITER], r[ITER];

    if (t < NBK) lcnt[t] = 0;
    __syncthreads();
    #pragma unroll
    for (int it = 0; it < ITER; ++it) {
        int e = base + it * 256 + t;
        if (e < E) {
            s[it] = src[e];
            d[it] = dst[e];
            r[it] = atomicAdd(&lcnt[d[it] >> shift], 1);
        }
    }
    __syncthreads();
    if (t < NBK) lbase[t] = lcnt[t] ? atomicAdd(&bcursor[t], lcnt[t]) : 0;
    __syncthreads();
    #pragma unroll
    for (int it = 0; it < ITER; ++it) {
        int e = base + it * 256 + t;
        if (e < E)
            epair[lbase[d[it] >> shift] + r[it]] = make_int2(s[it], d[it]);
    }
}

// degree histogram over bucket-ordered stream (atomics L2-hot)
__global__ __launch_bounds__(256) void count_deg_b(const int2* __restrict__ epair,
                                                   int* __restrict__ deg, int E) {
    int e = blockIdx.x * 256 + threadIdx.x;
    if (e < E) atomicAdd(&deg[epair[e].y], 1);
}

__global__ __launch_bounds__(256) void make_dinv(const int* __restrict__ deg,
                                                 float* __restrict__ dinv, int N) {
    int i = blockIdx.x * 256 + threadIdx.x;
    if (i < N) dinv[i] = rsqrtf((float)deg[i] + 1.0f);  // +1 = self-loop
}

// ---------------- per-node offsets (3-level scan over deg) ----------------

__global__ __launch_bounds__(256) void scan_block(const int* __restrict__ deg,
                                                  int* __restrict__ exc,
                                                  int* __restrict__ bsums, int N) {
    __shared__ int s[256];
    int base = blockIdx.x * 1024;
    int t = threadIdx.x;
    int v[4]; int sum = 0;
    #pragma unroll
    for (int k = 0; k < 4; ++k) {
        int idx = base + t * 4 + k;
        v[k] = (idx < N) ? deg[idx] : 0;
        sum += v[k];
    }
    s[t] = sum; __syncthreads();
    for (int off = 1; off < 256; off <<= 1) {
        int x = (t >= off) ? s[t - off] : 0;
        __syncthreads();
        s[t] += x;
        __syncthreads();
    }
    int run = s[t] - sum;
    #pragma unroll
    for (int k = 0; k < 4; ++k) {
        int idx = base + t * 4 + k;
        if (idx < N) exc[idx] = run;
        run += v[k];
    }
    if (t == 255) bsums[blockIdx.x] = s[255];
}

__global__ __launch_bounds__(256) void scan_sums(int* __restrict__ bsums, int nb) {
    __shared__ int s[256];
    int t = threadIdx.x;
    int v = (t < nb) ? bsums[t] : 0;
    s[t] = v; __syncthreads();
    for (int off = 1; off < 256; off <<= 1) {
        int x = (t >= off) ? s[t - off] : 0;
        __syncthreads();
        s[t] += x;
        __syncthreads();
    }
    if (t < nb) bsums[t] = s[t] - v;
}

__global__ __launch_bounds__(256) void scan_add(const int* __restrict__ bsums,
                                                int* __restrict__ exc_cursor,
                                                int* __restrict__ offs, int N, int E) {
    int i = blockIdx.x * 256 + threadIdx.x;
    if (i < N) {
        int o = exc_cursor[i] + bsums[i >> 10];
        offs[i] = o;
        exc_cursor[i] = o;  // becomes the per-node cursor
    }
    if (i == 0) offs[N] = E;
}

// fine scatter (counting sort, pass 2): bucket-ordered stream -> CSR esrc
__global__ __launch_bounds__(256) void fine_scatter(const int2* __restrict__ epair, int E,
                                                    int* __restrict__ cursor,
                                                    int* __restrict__ esrc) {
    int e = blockIdx.x * 256 + threadIdx.x;
    if (e < E) {
        int2 p = epair[e];
        int pos = atomicAdd(&cursor[p.y], 1);
        esrc[pos] = p.x;
    }
}

// ---------------- GEMM: H[M,NC](fp16) = X[M,128](fp32) @ W[128,NC], opt ReLU on X

template<int NC, bool RELU>
__global__ __launch_bounds__(256) void gemm_xw(const float* __restrict__ X,
                                               const float* __restrict__ W,
                                               __half* __restrict__ H, int M) {
    constexpr int BM = 128, BK = 32;
    constexpr int CPT = NC / 16;              // cols per thread: 8 (NC=128) / 4 (NC=64)
    __shared__ float sX[BK][BM + 4];
    __shared__ float sW[BK][NC];

    const int tid = threadIdx.x;
    const int tc = tid & 15, tr = tid >> 4;
    const int c0 = tc * CPT, r0 = tr * 8;
    const int row0 = blockIdx.x * BM;

    float acc[8][CPT];
    #pragma unroll
    for (int i = 0; i < 8; ++i)
        #pragma unroll
        for (int j = 0; j < CPT; ++j) acc[i][j] = 0.f;

    const int lfi = tid & 7;
    const int llr = tid >> 3;

    for (int kt = 0; kt < 128; kt += BK) {
        #pragma unroll
        for (int rr = 0; rr < 4; ++rr) {
            int lr = llr + rr * 32;
            int gr = row0 + lr;
            float4 v = make_float4(0.f, 0.f, 0.f, 0.f);
            if (gr < M) v = *reinterpret_cast<const float4*>(&X[(size_t)gr * 128 + kt + lfi * 4]);
            if (RELU) {
                v.x = fmaxf(v.x, 0.f); v.y = fmaxf(v.y, 0.f);
                v.z = fmaxf(v.z, 0.f); v.w = fmaxf(v.w, 0.f);
            }
            sX[lfi * 4 + 0][lr] = v.x;
            sX[lfi * 4 + 1][lr] = v.y;
            sX[lfi * 4 + 2][lr] = v.z;
            sX[lfi * 4 + 3][lr] = v.w;
        }
        {
            constexpr int F4 = (BK * NC / 4) / 256;
            #pragma unroll
            for (int q = 0; q < F4; ++q) {
                int idx = q * 256 + tid;
                int kr = idx / (NC / 4);
                int cc = (idx % (NC / 4)) * 4;
                *reinterpret_cast<float4*>(&sW[kr][cc]) =
                    *reinterpret_cast<const float4*>(&W[(size_t)(kt + kr) * NC + cc]);
            }
        }
        __syncthreads();

        #pragma unroll 8
        for (int k = 0; k < BK; ++k) {
            float a[8];
            *reinterpret_cast<float4*>(&a[0]) = *reinterpret_cast<const float4*>(&sX[k][r0]);
            *reinterpret_cast<float4*>(&a[4]) = *reinterpret_cast<const float4*>(&sX[k][r0 + 4]);
            float b[CPT];
            #pragma unroll
            for (int j = 0; j < CPT; j += 4)
                *reinterpret_cast<float4*>(&b[j]) = *reinterpret_cast<const float4*>(&sW[k][c0 + j]);
            #pragma unroll
            for (int i = 0; i < 8; ++i)
                #pragma unroll
                for (int j = 0; j < CPT; ++j)
                    acc[i][j] = fmaf(a[i], b[j], acc[i][j]);
        }
        __syncthreads();
    }

    #pragma unroll
    for (int i = 0; i < 8; ++i) {
        int gr = row0 + r0 + i;
        if (gr < M) {
            union { __half h[8]; uint4 u4; uint2 u2; } o;
            #pragma unroll
            for (int j = 0; j < CPT; ++j) o.h[j] = __float2half(acc[i][j]);
            if constexpr (CPT == 8)
                *reinterpret_cast<uint4*>(&H[(size_t)gr * NC + c0]) = o.u4;
            else
                *reinterpret_cast<uint2*>(&H[(size_t)gr * NC + c0]) = o.u2;
        }
    }
}

// ---------------- gather: AGG[i](fp32) = b + H[i]*dinv[i]^2 + sum_j H[s_j]*dinv[s_j]*dinv[i]

template<int C>
__global__ __launch_bounds__(256) void gather_nodes(const __half* __restrict__ H,
                                                    const int* __restrict__ esrc,
                                                    const int* __restrict__ offs,
                                                    const float* __restrict__ dinv,
                                                    const float* __restrict__ bias,
                                                    float* __restrict__ AGG, int N) {
    constexpr int TPN = C / 8;
    int gid = blockIdx.x * 256 + threadIdx.x;
    int node = gid / TPN;
    if (node >= N) return;
    int lane = gid % TPN;

    float di = dinv[node];
    float s2 = di * di;
    float acc[8];
    {
        uint4 raw = *reinterpret_cast<const uint4*>(H + (size_t)node * C + lane * 8);
        const __half2* h2 = reinterpret_cast<const __half2*>(&raw);
        #pragma unroll
        for (int q = 0; q < 4; ++q) {
            float2 f = __half22float2(h2[q]);
            acc[2*q]   = fmaf(f.x, s2, bias[lane * 8 + 2*q]);
            acc[2*q+1] = fmaf(f.y, s2, bias[lane * 8 + 2*q+1]);
        }
    }

    int j0 = offs[node], j1 = offs[node + 1];
    int j = j0;
    for (; j + 1 < j1; j += 2) {
        int s0 = esrc[j], s1 = esrc[j + 1];
        float n0 = dinv[s0] * di;
        float n1 = dinv[s1] * di;
        uint4 r0 = *reinterpret_cast<const uint4*>(H + (size_t)s0 * C + lane * 8);
        uint4 r1 = *reinterpret_cast<const uint4*>(H + (size_t)s1 * C + lane * 8);
        const __half2* a0 = reinterpret_cast<const __half2*>(&r0);
        const __half2* a1 = reinterpret_cast<const __half2*>(&r1);
        #pragma unroll
        for (int q = 0; q < 4; ++q) {
            float2 f0 = __half22float2(a0[q]);
            float2 f1 = __half22float2(a1[q]);
            acc[2*q]   = fmaf(f0.x, n0, acc[2*q]);
            acc[2*q+1] = fmaf(f0.y, n0, acc[2*q+1]);
            acc[2*q]   = fmaf(f1.x, n1, acc[2*q]);
            acc[2*q+1] = fmaf(f1.y, n1, acc[2*q+1]);
        }
    }
    if (j < j1) {
        int s0 = esrc[j];
        float n0 = dinv[s0] * di;
        uint4 r0 = *reinterpret_cast<const uint4*>(H + (size_t)s0 * C + lane * 8);
        const __half2* a0 = reinterpret_cast<const __half2*>(&r0);
        #pragma unroll
        for (int q = 0; q < 4; ++q) {
            float2 f0 = __half22float2(a0[q]);
            acc[2*q]   = fmaf(f0.x, n0, acc[2*q]);
            acc[2*q+1] = fmaf(f0.y, n0, acc[2*q+1]);
        }
    }

    float4* o = reinterpret_cast<float4*>(AGG + (size_t)node * C + lane * 8);
    o[0] = make_float4(acc[0], acc[1], acc[2], acc[3]);
    o[1] = make_float4(acc[4], acc[5], acc[6], acc[7]);
}

// ---------------- launch ----------------

extern "C" void kernel_launch(void* const* d_in, const int* in_sizes, int n_in,
                              void* d_out, int out_size, void* d_ws, size_t ws_size,
                              hipStream_t stream) {
    const float* x  = (const float*)d_in[0];
    const int*   ei = (const int*)d_in[1];   // int32 (JAX canonicalizes int64)
    const float* W1 = (const float*)d_in[2];
    const float* b1 = (const float*)d_in[3];
    const float* W2 = (const float*)d_in[4];
    const float* b2 = (const float*)d_in[5];
    float* out = (float*)d_out;

    const int N = in_sizes[0] / 128;
    const int E = in_sizes[1] / 2;
    const int* src = ei;
    const int* dst = ei + E;

    // coarse bucket shift: ((N-1)>>shift) < NBK
    int shift = 0;
    while (((long long)(N - 1) >> shift) >= NBK) ++shift;

    // workspace layout (4B units)
    int*    deg   = (int*)d_ws;                     // N
    int*    excur = deg + N;                        // N (scan -> per-node cursor)
    int*    bsums = excur + N;                      // 1024
    int*    offs  = bsums + 1024;                   // N+8
    float*  dinv  = (float*)(offs + N + 8);         // N
    int*    bcnt  = (int*)(dinv + N);               // NBK
    int*    bcur  = bcnt + NBK;                     // NBK
    int*    esrc  = bcur + NBK;                     // E
    int2*   epair = (int2*)(esrc + E);              // E pairs (dead before gemm1)
    __half* h1    = (__half*)epair;                 // N*128 halves (aliases epair)
    float*  agg1  = (float*)((int*)epair + (size_t)N * 64);  // N*128 floats
    __half* t2    = h1;                             // aliases h1 (dead by then)

    const int nb = (N + 1023) / 1024;

    // --- counting sort: coarse bucket pass ---
    hipMemsetAsync(deg, 0, (size_t)N * sizeof(int), stream);
    hipMemsetAsync(bcnt, 0, NBK * sizeof(int), stream);
    bucket_hist<<<512, 256, 0, stream>>>(dst, E, shift, bcnt);
    bucket_scan<<<1, NBK, 0, stream>>>(bcnt, bcur);
    bucket_scatter<<<(E + 4095) / 4096, 256, 0, stream>>>(src, dst, E, shift, bcur, epair);

    // --- degrees + per-node offsets (on bucket-ordered stream) ---
    count_deg_b<<<(E + 255) / 256, 256, 0, stream>>>(epair, deg, E);
    make_dinv<<<(N + 255) / 256, 256, 0, stream>>>(deg, dinv, N);
    scan_block<<<nb, 256, 0, stream>>>(deg, excur, bsums, N);
    scan_sums<<<1, 256, 0, stream>>>(bsums, nb);
    scan_add<<<(N + 255) / 256, 256, 0, stream>>>(bsums, excur, offs, N, E);

    // --- counting sort: fine pass (L2-hot cursor + dense write window) ---
    fine_scatter<<<(E + 255) / 256, 256, 0, stream>>>(epair, E, excur, esrc);

    // --- layer 1 ---
    gemm_xw<128, false><<<(N + 127) / 128, 256, 0, stream>>>(x, W1, h1, N);
    gather_nodes<128><<<(int)(((size_t)N * 16 + 255) / 256), 256, 0, stream>>>(
        h1, esrc, offs, dinv, b1, agg1, N);

    // --- layer 2 ---
    gemm_xw<64, true><<<(N + 127) / 128, 256, 0, stream>>>(agg1, W2, t2, N);
    gather_nodes<64><<<(int)(((size_t)N * 8 + 255) / 256), 256, 0, stream>>>(
        t2, esrc, offs, dinv, b2, out, N);
}